// Round 1
// 391.476 us; speedup vs baseline: 1.3508x; 1.3508x over previous
//
#include <hip/hip_runtime.h>

// LISTA fused kernel, MI355X gfx950.
// Shapes: X[4][64][65536] f32, We[256][64] f32, S[3][256][256] f32, thetas[4] f32,
// out[4][256][65536] f32.  M = 4*65536 = 262144 pixels.
//
// R1: occupancy push. 512-thread blocks (8 waves), each wave owns a 32-dict
// slice (dt=2) of the same TM=64 pixel tile -> per-wave reg state halved
// (acc 32 + B0pk 16 + staggered S frags) so arch+acc regs fit 128 ->
// 4 waves/SIMD (16 waves/CU) vs previous 2. S fragments are prefetched in a
// software pipeline (ks0-1 issued before the previous epilogue; ks+2 issued
// inside the MFMA loop). Prepass stores bf16 weights in exact fragment order
// so every S-fragment load is one coalesced 1KB dwordx4 across the wave.
// Epilogue shrink via v_med3_f32 (x - med3(x,-th,th)).

#define TM 64
#define LA_STRIDE 264   // 256 + 8 bf16 pad: 528B rows, 2-way banks (free)
#define LX_STRIDE 72    // 64 + 8

typedef short bf16x8 __attribute__((ext_vector_type(8)));
typedef float f32x4 __attribute__((ext_vector_type(4)));

__device__ __forceinline__ unsigned short f2bf(float f) {
  union { float f; unsigned u; } a; a.f = f;
  return (unsigned short)((a.u + 0x7fffu + ((a.u >> 16) & 1u)) >> 16); // RNE
}
__device__ __forceinline__ float bf2f(unsigned hbits16) {
  union { unsigned u; float f; } a; a.u = hbits16 << 16; return a.f;
}
__device__ __forceinline__ float sshrink(float x, float th) {
  // softshrink: x - clamp(x, -th, th); med3 is the clamp idiom (1 VALU op)
  return x - __builtin_amdgcn_fmed3f(x, -th, th);
}

__device__ __forceinline__ bf16x8 cvt8(const float* p) {
  float4 f0 = *reinterpret_cast<const float4*>(p);
  float4 f1 = *reinterpret_cast<const float4*>(p + 4);
  bf16x8 t;
  t[0] = (short)f2bf(f0.x); t[1] = (short)f2bf(f0.y);
  t[2] = (short)f2bf(f0.z); t[3] = (short)f2bf(f0.w);
  t[4] = (short)f2bf(f1.x); t[5] = (short)f2bf(f1.y);
  t[6] = (short)f2bf(f1.z); t[7] = (short)f2bf(f1.w);
  return t;
}

// Prepass: bf16-convert We and S, permuted to fragment order so that a wave's
// A-fragment load for (frag, lane) is wbase[frag*512 + lane*8] (16B/lane,
// 1KB contiguous per wave).
//   We frag id: ds*2 + ks            (ds = d>>4, ks over K=64)
//   S  frag id: (it*16 + ds)*8 + ks  (ks over K=256)
// In-frag: lane = quad*16 + l16 holds rows d = ds*16+l16, cols ks*32+quad*8+e.
__global__ void convert_weights(const float* __restrict__ We,
                                const float* __restrict__ S,
                                unsigned short* __restrict__ w) {
  int gid = blockIdx.x * 256 + threadIdx.x;
  if (gid < 256 * 64) {
    int d = gid >> 6, c = gid & 63;
    int ds = d >> 4, l16 = d & 15;
    int ks = c >> 5, quad = (c >> 3) & 3, e = c & 7;
    int dst = ((ds * 2 + ks) * 64 + quad * 16 + l16) * 8 + e;
    w[dst] = f2bf(We[gid]);
  } else if (gid < 256 * 64 + 3 * 256 * 256) {
    int sidx = gid - 256 * 64;
    int it = sidx >> 16, r = sidx & 65535;
    int d = r >> 8, c = r & 255;
    int ds = d >> 4, l16 = d & 15;
    int ks = c >> 5, quad = (c >> 3) & 3, e = c & 7;
    int dst = (((it * 16 + ds) * 8 + ks) * 64 + quad * 16 + l16) * 8 + e;
    w[256 * 64 + dst] = f2bf(S[sidx]);
  }
}

template<bool WBF16>
__device__ __forceinline__ bf16x8 load_we(const unsigned short* wWe, const float* Wef,
                                          int wave, int dt, int ks,
                                          int lane, int l16, int quad) {
  if constexpr (WBF16) {
    return *reinterpret_cast<const bf16x8*>(
        wWe + (((wave * 2 + dt) * 2 + ks) * 64 + lane) * 8);
  } else {
    return cvt8(Wef + (wave * 32 + dt * 16 + l16) * 64 + ks * 32 + quad * 8);
  }
}

template<bool WBF16>
__device__ __forceinline__ bf16x8 load_s(const unsigned short* wS, const float* Sf,
                                         int it, int dslice, int ks,
                                         int lane, int l16, int quad) {
  if constexpr (WBF16) {
    return *reinterpret_cast<const bf16x8*>(
        wS + (((it * 16 + dslice) * 8 + ks) * 64 + lane) * 8);
  } else {
    return cvt8(Sf + it * 65536 + (dslice * 16 + l16) * 256 + ks * 32 + quad * 8);
  }
}

template<bool WBF16>
__global__ __launch_bounds__(512, 4)
void lista_kernel(const float* __restrict__ X, const float* __restrict__ Wef,
                  const float* __restrict__ Sf, const float* __restrict__ thetas,
                  float* __restrict__ out,
                  const unsigned short* __restrict__ wWe,
                  const unsigned short* __restrict__ wS) {
  __shared__ unsigned short lA[TM * LA_STRIDE]; // logits tile [pixel][dict], bf16
  __shared__ unsigned short lX[TM * LX_STRIDE]; // input tile  [pixel][chan], bf16

  const int tid  = threadIdx.x;
  const int wave = tid >> 6;        // 0..7
  const int lane = tid & 63;
  const int l16  = lane & 15;
  const int quad = lane >> 4;
  const int p0   = blockIdx.x * TM;
  const int b0   = p0 >> 16;        // image index (65536 spatials per image)
  const int s0   = p0 & 65535;      // spatial offset within image
  const int d_base  = wave * 32;    // this wave's 32-row dict slice
  const int ds_base = wave * 2;     // in units of 16-row tiles

  float ths[4];
#pragma unroll
  for (int i = 0; i < 4; ++i) ths[i] = thetas[i];

  // ---- stage X tile -> lX (bf16). Each thread: 8 coalesced loads (fixed c,
  // 64 consecutive spatials across the wave), one ds_write_b128.
  {
    const int c0 = wave * 8;
    float v[8];
#pragma unroll
    for (int j = 0; j < 8; ++j)
      v[j] = X[(size_t)(b0 * 64 + c0 + j) * 65536 + s0 + lane];
    bf16x8 pk;
#pragma unroll
    for (int j = 0; j < 8; ++j) pk[j] = (short)f2bf(v[j]);
    *reinterpret_cast<bf16x8*>(&lX[lane * LX_STRIDE + c0]) = pk;
  }

  // ---- We fragments for GEMM1 (A-operand), 4 frags = 16 VGPRs
  bf16x8 Wf1[2][2];
#pragma unroll
  for (int dt = 0; dt < 2; ++dt)
#pragma unroll
    for (int ks = 0; ks < 2; ++ks)
      Wf1[dt][ks] = load_we<WBF16>(wWe, Wef, wave, dt, ks, lane, l16, quad);

  __syncthreads();

  // ---- GEMM1: B0[d][p] = sum_c We[d][c] * X[p][c]
  f32x4 acc[2][4];
#pragma unroll
  for (int dt = 0; dt < 2; ++dt)
#pragma unroll
    for (int pt = 0; pt < 4; ++pt) acc[dt][pt] = (f32x4){0.f, 0.f, 0.f, 0.f};

#pragma unroll
  for (int ks = 0; ks < 2; ++ks) {
    bf16x8 bfr[4];
#pragma unroll
    for (int pt = 0; pt < 4; ++pt)
      bfr[pt] = *reinterpret_cast<const bf16x8*>(
          &lX[(pt * 16 + l16) * LX_STRIDE + ks * 32 + quad * 8]);
#pragma unroll
    for (int pt = 0; pt < 4; ++pt)
#pragma unroll
      for (int dt = 0; dt < 2; ++dt)
        acc[dt][pt] = __builtin_amdgcn_mfma_f32_16x16x32_bf16(
            Wf1[dt][ks], bfr[pt], acc[dt][pt], 0, 0, 0);
  }

  // ---- prefetch S[0] ks0-1 (hidden under phase-0 epilogue + barrier)
  bf16x8 Wfp[2][2];
#pragma unroll
  for (int dt = 0; dt < 2; ++dt)
#pragma unroll
    for (int ks = 0; ks < 2; ++ks)
      Wfp[dt][ks] = load_s<WBF16>(wS, Sf, 0, ds_base + dt, ks, lane, l16, quad);

  // ---- phase-0 epilogue: keep B0 packed bf16 in regs; logits0 = shrink(B0) -> lA
  const float th0 = ths[0];
  unsigned B0pk[2][4][2];
#pragma unroll
  for (int dt = 0; dt < 2; ++dt)
#pragma unroll
    for (int pt = 0; pt < 4; ++pt) {
      float v0 = acc[dt][pt][0], v1 = acc[dt][pt][1];
      float v2 = acc[dt][pt][2], v3 = acc[dt][pt][3];
      B0pk[dt][pt][0] = (unsigned)f2bf(v0) | ((unsigned)f2bf(v1) << 16);
      B0pk[dt][pt][1] = (unsigned)f2bf(v2) | ((unsigned)f2bf(v3) << 16);
      float l0 = sshrink(v0, th0), l1 = sshrink(v1, th0);
      float l2 = sshrink(v2, th0), l3 = sshrink(v3, th0);
      unsigned pk0 = (unsigned)f2bf(l0) | ((unsigned)f2bf(l1) << 16);
      unsigned pk1 = (unsigned)f2bf(l2) | ((unsigned)f2bf(l3) << 16);
      const int row = pt * 16 + l16;
      const int col = d_base + dt * 16 + quad * 4;
      *reinterpret_cast<uint2*>(&lA[row * LA_STRIDE + col]) = make_uint2(pk0, pk1);
    }

  // ---- LISTA iterations (fully unrolled; all array indices static)
#pragma unroll
  for (int it = 0; it < 3; ++it) {
    const float th = ths[it + 1];
    __syncthreads(); // lA writes -> this iter's reads

#pragma unroll
    for (int dt = 0; dt < 2; ++dt)
#pragma unroll
      for (int pt = 0; pt < 4; ++pt) acc[dt][pt] = (f32x4){0.f, 0.f, 0.f, 0.f};

    // staggered K-loop: issue loads for ks+2 before computing ks
    bf16x8 Wfc[2][6];
#pragma unroll
    for (int ks = 0; ks < 8; ++ks) {
      if (ks < 6) {
#pragma unroll
        for (int dt = 0; dt < 2; ++dt)
          Wfc[dt][ks] = load_s<WBF16>(wS, Sf, it, ds_base + dt, ks + 2,
                                      lane, l16, quad);
      }
      bf16x8 bfr[4];
#pragma unroll
      for (int pt = 0; pt < 4; ++pt)
        bfr[pt] = *reinterpret_cast<const bf16x8*>(
            &lA[(pt * 16 + l16) * LA_STRIDE + ks * 32 + quad * 8]);
#pragma unroll
      for (int pt = 0; pt < 4; ++pt)
#pragma unroll
        for (int dt = 0; dt < 2; ++dt) {
          bf16x8 a = (ks < 2) ? Wfp[dt][ks] : Wfc[dt][ks - 2];
          acc[dt][pt] = __builtin_amdgcn_mfma_f32_16x16x32_bf16(
              a, bfr[pt], acc[dt][pt], 0, 0, 0);
        }
    }

    __syncthreads(); // all waves done reading lA before it is overwritten

    // prefetch next iter's ks0-1 before the epilogue (hides L2 latency)
    if (it < 2) {
#pragma unroll
      for (int dt = 0; dt < 2; ++dt)
#pragma unroll
        for (int ks = 0; ks < 2; ++ks)
          Wfp[dt][ks] = load_s<WBF16>(wS, Sf, it + 1, ds_base + dt, ks,
                                      lane, l16, quad);
    }

#pragma unroll
    for (int dt = 0; dt < 2; ++dt)
#pragma unroll
      for (int pt = 0; pt < 4; ++pt) {
        float b0v0 = bf2f(B0pk[dt][pt][0] & 0xffffu);
        float b0v1 = bf2f(B0pk[dt][pt][0] >> 16);
        float b0v2 = bf2f(B0pk[dt][pt][1] & 0xffffu);
        float b0v3 = bf2f(B0pk[dt][pt][1] >> 16);
        float l0 = sshrink(acc[dt][pt][0] + b0v0, th);
        float l1 = sshrink(acc[dt][pt][1] + b0v1, th);
        float l2 = sshrink(acc[dt][pt][2] + b0v2, th);
        float l3 = sshrink(acc[dt][pt][3] + b0v3, th);
        if (it < 2) {
          unsigned pk0 = (unsigned)f2bf(l0) | ((unsigned)f2bf(l1) << 16);
          unsigned pk1 = (unsigned)f2bf(l2) | ((unsigned)f2bf(l3) << 16);
          const int row = pt * 16 + l16;
          const int col = d_base + dt * 16 + quad * 4;
          *reinterpret_cast<uint2*>(&lA[row * LA_STRIDE + col]) = make_uint2(pk0, pk1);
        } else {
          // out[b][d][s]: 16 lanes of a quad write 64B contiguous spatials
          const int d = d_base + dt * 16 + quad * 4;
          const size_t ob = (size_t)(b0 * 256 + d) * 65536 + s0 + pt * 16 + l16;
          out[ob] = l0;
          out[ob + 65536] = l1;
          out[ob + 2 * 65536] = l2;
          out[ob + 3 * 65536] = l3;
        }
      }
  }
}

extern "C" void kernel_launch(void* const* d_in, const int* in_sizes, int n_in,
                              void* d_out, int out_size, void* d_ws, size_t ws_size,
                              hipStream_t stream) {
  const float* X  = (const float*)d_in[0];
  const float* We = (const float*)d_in[1];
  const float* S  = (const float*)d_in[2];
  const float* th = (const float*)d_in[3];
  float* out = (float*)d_out;

  const size_t welems = 256 * 64 + 3 * 256 * 256; // 212992
  const bool wb = ws_size >= welems * 2;

  if (wb) {
    unsigned short* w = (unsigned short*)d_ws;
    convert_weights<<<dim3(832), dim3(256), 0, stream>>>(We, S, w);
    lista_kernel<true><<<dim3(4096), dim3(512), 0, stream>>>(
        X, We, S, th, out, w, w + 256 * 64);
  } else {
    lista_kernel<false><<<dim3(4096), dim3(512), 0, stream>>>(
        X, We, S, th, out, nullptr, nullptr);
  }
}

// Round 3
// 380.278 us; speedup vs baseline: 1.3906x; 1.0294x over previous
//
#include <hip/hip_runtime.h>
#include <hip/hip_bf16.h>

// LISTA fused kernel, MI355X gfx950.
// Shapes: X[4][64][65536] f32, We[256][64] f32, S[3][256][256] f32, thetas[4] f32,
// out[4][256][65536] f32.  M = 4*65536 = 262144 pixels.
//
// R2 (resubmit after container-level bench failure; no kernel signal):
//  - Double-buffered lA (2x33.8KB + lX = 76.8KB/block, 2 blocks/CU = 153.6KB):
//    iter i reads buf (i&1), writes buf (i&1)^1 -> one barrier per phase
//    (4 total vs 7), so epilogue VALU overlaps other waves' MFMA/LDS.
//  - HW bf16 conversion (v_cvt_pk_bf16_f32 via __float22bfloat162_rn) replaces
//    manual RNE bit math: ~8 VALU/pair -> 1. Same RNE numerics.
// Kept from R1: 512 thr (8 waves x 32-dict slice), fragment-order bf16 weight
// prepass (1KB coalesced S-frag loads), staggered S prefetch, med3 shrink.

#define TM 64
#define LA_STRIDE 264   // 256 + 8 bf16 pad: 528B rows, 2-way banks (free)
#define LX_STRIDE 72    // 64 + 8

typedef short bf16x8 __attribute__((ext_vector_type(8)));
typedef float f32x4 __attribute__((ext_vector_type(4)));

static __device__ __forceinline__ unsigned short f2bf(float f) {
  union { __hip_bfloat16 h; unsigned short u; } c;
  c.h = __float2bfloat16(f);  // RNE, single v_cvt
  return c.u;
}
static __device__ __forceinline__ unsigned pkbf(float a, float b) {
  union { __hip_bfloat162 h; unsigned u; } c;
  c.h = __float22bfloat162_rn(float2{a, b});  // v_cvt_pk_bf16_f32
  return c.u;
}
static __device__ __forceinline__ float bflo(unsigned u) {
  union { unsigned u; float f; } c; c.u = u << 16; return c.f;
}
static __device__ __forceinline__ float bfhi(unsigned u) {
  union { unsigned u; float f; } c; c.u = u & 0xffff0000u; return c.f;
}
static __device__ __forceinline__ float sshrink(float x, float th) {
  // softshrink: x - clamp(x, -th, th); med3 is the clamp idiom (1 VALU op)
  return x - __builtin_amdgcn_fmed3f(x, -th, th);
}

static __device__ __forceinline__ bf16x8 cvt8(const float* p) {
  float4 f0 = *reinterpret_cast<const float4*>(p);
  float4 f1 = *reinterpret_cast<const float4*>(p + 4);
  bf16x8 t;
  t[0] = (short)f2bf(f0.x); t[1] = (short)f2bf(f0.y);
  t[2] = (short)f2bf(f0.z); t[3] = (short)f2bf(f0.w);
  t[4] = (short)f2bf(f1.x); t[5] = (short)f2bf(f1.y);
  t[6] = (short)f2bf(f1.z); t[7] = (short)f2bf(f1.w);
  return t;
}

// Prepass: bf16-convert We and S, permuted to fragment order so that a wave's
// A-fragment load for (frag, lane) is wbase[frag*512 + lane*8] (16B/lane,
// 1KB contiguous per wave).
//   We frag id: ds*2 + ks            (ds = d>>4, ks over K=64)
//   S  frag id: (it*16 + ds)*8 + ks  (ks over K=256)
// In-frag: lane = quad*16 + l16 holds rows d = ds*16+l16, cols ks*32+quad*8+e.
__global__ void convert_weights(const float* __restrict__ We,
                                const float* __restrict__ S,
                                unsigned short* __restrict__ w) {
  int gid = blockIdx.x * 256 + threadIdx.x;
  if (gid < 256 * 64) {
    int d = gid >> 6, c = gid & 63;
    int ds = d >> 4, l16 = d & 15;
    int ks = c >> 5, quad = (c >> 3) & 3, e = c & 7;
    int dst = ((ds * 2 + ks) * 64 + quad * 16 + l16) * 8 + e;
    w[dst] = f2bf(We[gid]);
  } else if (gid < 256 * 64 + 3 * 256 * 256) {
    int sidx = gid - 256 * 64;
    int it = sidx >> 16, r = sidx & 65535;
    int d = r >> 8, c = r & 255;
    int ds = d >> 4, l16 = d & 15;
    int ks = c >> 5, quad = (c >> 3) & 3, e = c & 7;
    int dst = (((it * 16 + ds) * 8 + ks) * 64 + quad * 16 + l16) * 8 + e;
    w[256 * 64 + dst] = f2bf(S[sidx]);
  }
}

template<bool WBF16>
__device__ __forceinline__ bf16x8 load_we(const unsigned short* wWe, const float* Wef,
                                          int wave, int dt, int ks,
                                          int lane, int l16, int quad) {
  if constexpr (WBF16) {
    return *reinterpret_cast<const bf16x8*>(
        wWe + (((wave * 2 + dt) * 2 + ks) * 64 + lane) * 8);
  } else {
    return cvt8(Wef + (wave * 32 + dt * 16 + l16) * 64 + ks * 32 + quad * 8);
  }
}

template<bool WBF16>
__device__ __forceinline__ bf16x8 load_s(const unsigned short* wS, const float* Sf,
                                         int it, int dslice, int ks,
                                         int lane, int l16, int quad) {
  if constexpr (WBF16) {
    return *reinterpret_cast<const bf16x8*>(
        wS + (((it * 16 + dslice) * 8 + ks) * 64 + lane) * 8);
  } else {
    return cvt8(Sf + it * 65536 + (dslice * 16 + l16) * 256 + ks * 32 + quad * 8);
  }
}

template<bool WBF16>
__global__ __launch_bounds__(512, 4)
void lista_kernel(const float* __restrict__ X, const float* __restrict__ Wef,
                  const float* __restrict__ Sf, const float* __restrict__ thetas,
                  float* __restrict__ out,
                  const unsigned short* __restrict__ wWe,
                  const unsigned short* __restrict__ wS) {
  __shared__ unsigned short lA[2][TM * LA_STRIDE]; // logits [pixel][dict] bf16, dbuf
  __shared__ unsigned short lX[TM * LX_STRIDE];    // input  [pixel][chan] bf16

  const int tid  = threadIdx.x;
  const int wave = tid >> 6;        // 0..7
  const int lane = tid & 63;
  const int l16  = lane & 15;
  const int quad = lane >> 4;
  const int p0   = blockIdx.x * TM;
  const int b0   = p0 >> 16;        // image index (65536 spatials per image)
  const int s0   = p0 & 65535;      // spatial offset within image
  const int d_base  = wave * 32;    // this wave's 32-row dict slice
  const int ds_base = wave * 2;     // in units of 16-row tiles

  float ths[4];
#pragma unroll
  for (int i = 0; i < 4; ++i) ths[i] = thetas[i];

  // ---- stage X tile -> lX (bf16). Each thread: 8 coalesced loads (fixed c,
  // 64 consecutive spatials across the wave), one ds_write_b128.
  {
    const int c0 = wave * 8;
    float v[8];
#pragma unroll
    for (int j = 0; j < 8; ++j)
      v[j] = X[(size_t)(b0 * 64 + c0 + j) * 65536 + s0 + lane];
    unsigned pk[4];
#pragma unroll
    for (int j = 0; j < 4; ++j) pk[j] = pkbf(v[2 * j], v[2 * j + 1]);
    *reinterpret_cast<uint4*>(&lX[lane * LX_STRIDE + c0]) =
        make_uint4(pk[0], pk[1], pk[2], pk[3]);
  }

  // ---- We fragments for GEMM1 (A-operand), 4 frags = 16 VGPRs
  bf16x8 Wf1[2][2];
#pragma unroll
  for (int dt = 0; dt < 2; ++dt)
#pragma unroll
    for (int ks = 0; ks < 2; ++ks)
      Wf1[dt][ks] = load_we<WBF16>(wWe, Wef, wave, dt, ks, lane, l16, quad);

  __syncthreads();

  // ---- GEMM1: B0[d][p] = sum_c We[d][c] * X[p][c]
  f32x4 acc[2][4];
#pragma unroll
  for (int dt = 0; dt < 2; ++dt)
#pragma unroll
    for (int pt = 0; pt < 4; ++pt) acc[dt][pt] = (f32x4){0.f, 0.f, 0.f, 0.f};

#pragma unroll
  for (int ks = 0; ks < 2; ++ks) {
    bf16x8 bfr[4];
#pragma unroll
    for (int pt = 0; pt < 4; ++pt)
      bfr[pt] = *reinterpret_cast<const bf16x8*>(
          &lX[(pt * 16 + l16) * LX_STRIDE + ks * 32 + quad * 8]);
#pragma unroll
    for (int pt = 0; pt < 4; ++pt)
#pragma unroll
      for (int dt = 0; dt < 2; ++dt)
        acc[dt][pt] = __builtin_amdgcn_mfma_f32_16x16x32_bf16(
            Wf1[dt][ks], bfr[pt], acc[dt][pt], 0, 0, 0);
  }

  // ---- prefetch S[0] ks0-1 (hidden under phase-0 epilogue)
  bf16x8 Wfp[2][2];
#pragma unroll
  for (int dt = 0; dt < 2; ++dt)
#pragma unroll
    for (int ks = 0; ks < 2; ++ks)
      Wfp[dt][ks] = load_s<WBF16>(wS, Sf, 0, ds_base + dt, ks, lane, l16, quad);

  // ---- phase-0 epilogue: keep B0 packed bf16 in regs; logits0 = shrink(B0) -> lA[0]
  const float th0 = ths[0];
  unsigned B0pk[2][4][2];
#pragma unroll
  for (int dt = 0; dt < 2; ++dt)
#pragma unroll
    for (int pt = 0; pt < 4; ++pt) {
      float v0 = acc[dt][pt][0], v1 = acc[dt][pt][1];
      float v2 = acc[dt][pt][2], v3 = acc[dt][pt][3];
      B0pk[dt][pt][0] = pkbf(v0, v1);
      B0pk[dt][pt][1] = pkbf(v2, v3);
      unsigned pk0 = pkbf(sshrink(v0, th0), sshrink(v1, th0));
      unsigned pk1 = pkbf(sshrink(v2, th0), sshrink(v3, th0));
      const int row = pt * 16 + l16;
      const int col = d_base + dt * 16 + quad * 4;
      *reinterpret_cast<uint2*>(&lA[0][row * LA_STRIDE + col]) = make_uint2(pk0, pk1);
    }

  // ---- LISTA iterations (fully unrolled; all array indices static)
#pragma unroll
  for (int it = 0; it < 3; ++it) {
    const float th = ths[it + 1];
    const int rb = it & 1;      // 0,1,0
    const int wbuf = rb ^ 1;

    __syncthreads(); // rb-buffer writes (previous phase) -> this iter's reads

#pragma unroll
    for (int dt = 0; dt < 2; ++dt)
#pragma unroll
      for (int pt = 0; pt < 4; ++pt) acc[dt][pt] = (f32x4){0.f, 0.f, 0.f, 0.f};

    // staggered K-loop: issue loads for ks+2 before computing ks
    bf16x8 Wfc[2][6];
#pragma unroll
    for (int ks = 0; ks < 8; ++ks) {
      if (ks < 6) {
#pragma unroll
        for (int dt = 0; dt < 2; ++dt)
          Wfc[dt][ks] = load_s<WBF16>(wS, Sf, it, ds_base + dt, ks + 2,
                                      lane, l16, quad);
      }
      bf16x8 bfr[4];
#pragma unroll
      for (int pt = 0; pt < 4; ++pt)
        bfr[pt] = *reinterpret_cast<const bf16x8*>(
            &lA[rb][(pt * 16 + l16) * LA_STRIDE + ks * 32 + quad * 8]);
#pragma unroll
      for (int pt = 0; pt < 4; ++pt)
#pragma unroll
        for (int dt = 0; dt < 2; ++dt) {
          bf16x8 a = (ks < 2) ? Wfp[dt][ks] : Wfc[dt][ks - 2];
          acc[dt][pt] = __builtin_amdgcn_mfma_f32_16x16x32_bf16(
              a, bfr[pt], acc[dt][pt], 0, 0, 0);
        }
    }

    // prefetch next iter's ks0-1 (hides L2 latency under the epilogue)
    if (it < 2) {
#pragma unroll
      for (int dt = 0; dt < 2; ++dt)
#pragma unroll
        for (int ks = 0; ks < 2; ++ks)
          Wfp[dt][ks] = load_s<WBF16>(wS, Sf, it + 1, ds_base + dt, ks,
                                      lane, l16, quad);
    }

    // epilogue: writes go to the OTHER buffer -> no second barrier needed
#pragma unroll
    for (int dt = 0; dt < 2; ++dt)
#pragma unroll
      for (int pt = 0; pt < 4; ++pt) {
        float b0v0 = bflo(B0pk[dt][pt][0]);
        float b0v1 = bfhi(B0pk[dt][pt][0]);
        float b0v2 = bflo(B0pk[dt][pt][1]);
        float b0v3 = bfhi(B0pk[dt][pt][1]);
        float l0 = sshrink(acc[dt][pt][0] + b0v0, th);
        float l1 = sshrink(acc[dt][pt][1] + b0v1, th);
        float l2 = sshrink(acc[dt][pt][2] + b0v2, th);
        float l3 = sshrink(acc[dt][pt][3] + b0v3, th);
        if (it < 2) {
          unsigned pk0 = pkbf(l0, l1);
          unsigned pk1 = pkbf(l2, l3);
          const int row = pt * 16 + l16;
          const int col = d_base + dt * 16 + quad * 4;
          *reinterpret_cast<uint2*>(&lA[wbuf][row * LA_STRIDE + col]) =
              make_uint2(pk0, pk1);
        } else {
          // out[b][d][s]: 16 lanes of a quad write 64B contiguous spatials
          const int d = d_base + dt * 16 + quad * 4;
          const size_t ob = (size_t)(b0 * 256 + d) * 65536 + s0 + pt * 16 + l16;
          out[ob] = l0;
          out[ob + 65536] = l1;
          out[ob + 2 * 65536] = l2;
          out[ob + 3 * 65536] = l3;
        }
      }
  }
}

extern "C" void kernel_launch(void* const* d_in, const int* in_sizes, int n_in,
                              void* d_out, int out_size, void* d_ws, size_t ws_size,
                              hipStream_t stream) {
  const float* X  = (const float*)d_in[0];
  const float* We = (const float*)d_in[1];
  const float* S  = (const float*)d_in[2];
  const float* th = (const float*)d_in[3];
  float* out = (float*)d_out;

  const size_t welems = 256 * 64 + 3 * 256 * 256; // 212992
  const bool wb = ws_size >= welems * 2;

  if (wb) {
    unsigned short* w = (unsigned short*)d_ws;
    convert_weights<<<dim3(832), dim3(256), 0, stream>>>(We, S, w);
    lista_kernel<true><<<dim3(4096), dim3(512), 0, stream>>>(
        X, We, S, th, out, w, w + 256 * 64);
  } else {
    lista_kernel<false><<<dim3(4096), dim3(512), 0, stream>>>(
        X, We, S, th, out, nullptr, nullptr);
  }
}